// Round 6
// baseline (770.340 us; speedup 1.0000x reference)
//
#include <hip/hip_runtime.h>

namespace {
constexpr int B = 4, C = 64, H = 512, W = 512;
constexpr int HW = H * W;                 // 2^18
constexpr int ND = B * HW;                // 2^20 sources == destinations
constexpr float EPS = 1e-5f;
constexpr int KT = 16;                    // heavy-destination threshold
constexpr int HEAVY_CAP = 65536;          // >= ND/(KT+1) = 61680, pigeonhole-safe

using u32x4 = __attribute__((ext_vector_type(4))) unsigned int;
using f32x4 = __attribute__((ext_vector_type(4))) float;
using i32x4 = __attribute__((ext_vector_type(4))) int;

__device__ __forceinline__ float bf16_lo(unsigned int u) {
    return __uint_as_float(u << 16);
}
__device__ __forceinline__ float bf16_hi(unsigned int u) {
    return __uint_as_float(u & 0xffff0000u);
}
__device__ __forceinline__ unsigned int pack_bf16(float a, float b) {
    unsigned int ua = __float_as_uint(a), ub = __float_as_uint(b);
    ua = (ua + 0x7fffu + ((ua >> 16) & 1u)) >> 16;   // RNE f32->bf16
    ub = (ub + 0x7fffu + ((ub >> 16) & 1u)) >> 16;
    return ua | (ub << 16);
}

// ---------------- fast path: sort records, then stream-gather --------------

// 4 pixels per thread, float4 x-loads
__global__ __launch_bounds__(256) void conv_kernel(
    const float* __restrict__ x, const float* __restrict__ wmat,
    const float* __restrict__ bias,
    float* __restrict__ att_a, int* __restrict__ idx_a,
    int* __restrict__ count,
    float* __restrict__ offset, float* __restrict__ dest)
{
    __shared__ float wsh[3 * C];
    int t = threadIdx.x;
    if (t < 3 * C) wsh[t] = wmat[t];
    __syncthreads();

    int s0 = (blockIdx.x * 256 + t) * 4;  // first of 4 consecutive sources
    int b = s0 >> 18;
    int p0 = s0 & (HW - 1);
    int hh = p0 >> 9, ww = p0 & (W - 1);  // 4|W so all 4 share the row

    const float* xb = x + (size_t)b * C * HW + p0;
    float a0[4] = {0.f, 0.f, 0.f, 0.f};
    float a1[4] = {0.f, 0.f, 0.f, 0.f};
    float a2[4] = {0.f, 0.f, 0.f, 0.f};
#pragma unroll
    for (int c = 0; c < C; ++c) {
        f32x4 v = *reinterpret_cast<const f32x4*>(xb + (size_t)c * HW);
        float w0 = wsh[c], w1 = wsh[C + c], w2 = wsh[2 * C + c];
#pragma unroll
        for (int j = 0; j < 4; ++j) {
            a0[j] = fmaf(v[j], w0, a0[j]);
            a1[j] = fmaf(v[j], w1, a1[j]);
            a2[j] = fmaf(v[j], w2, a2[j]);
        }
    }
    float b0 = bias[0], b1 = bias[1], b2 = bias[2];

    f32x4 offy, offx, attv, dyv, dxv;
    i32x4 idxv;
#pragma unroll
    for (int j = 0; j < 4; ++j) {
        float oy = (a0[j] + b0) * (float)H;    // DOWNSAMPLE = 1.0
        float ox = (a1[j] + b1) * (float)W;
        float at = expf(a2[j] + b2);
        int dy = (int)rintf((float)hh + oy);   // RNE == jnp.round
        dy = min(max(dy, 0), H - 1);
        int dx = (int)rintf((float)(ww + j) + ox);
        dx = min(max(dx, 0), W - 1);
        offy[j] = oy; offx[j] = ox; attv[j] = at;
        dyv[j] = (float)dy; dxv[j] = (float)dx;
        idxv[j] = dy * W + dx;
        atomicAdd(&count[(b << 18) | idxv[j]], 1);
    }
    size_t ob = (size_t)b * 2 * HW;
    *reinterpret_cast<f32x4*>(offset + ob + p0)      = offy;
    *reinterpret_cast<f32x4*>(offset + ob + HW + p0) = offx;
    *reinterpret_cast<f32x4*>(dest + ob + p0)        = dyv;
    *reinterpret_cast<f32x4*>(dest + ob + HW + p0)   = dxv;
    *reinterpret_cast<f32x4*>(att_a + s0)            = attv;
    *reinterpret_cast<i32x4*>(idx_a + s0)            = idxv;
}

__global__ __launch_bounds__(256) void scan_alloc_kernel(
    const int* __restrict__ count, int* __restrict__ base,
    int* __restrict__ cursor, int* __restrict__ alloc)
{
    __shared__ int sd[256];
    __shared__ int blockBase;
    int t = threadIdx.x;
    int i = blockIdx.x * 256 + t;
    int c = count[i];
    sd[t] = c;
    __syncthreads();
#pragma unroll
    for (int off = 1; off < 256; off <<= 1) {     // Hillis-Steele inclusive
        int v = (t >= off) ? sd[t - off] : 0;
        __syncthreads();
        sd[t] += v;
        __syncthreads();
    }
    if (t == 255) blockBase = atomicAdd(alloc, sd[255]);
    __syncthreads();
    int bb = blockBase + sd[t] - c;
    base[i] = bb;
    cursor[i] = bb;
}

// re-read x, premultiply, nt-write bf16 record into its sorted CSR slot
__global__ __launch_bounds__(256) void sortcopy_kernel(
    const float* __restrict__ x, const float* __restrict__ att_a,
    const int* __restrict__ idx_a, int* __restrict__ cursor,
    u32x4* __restrict__ rec, float* __restrict__ att_s)
{
    int s = blockIdx.x * 256 + threadIdx.x;
    int b = s >> 18;
    int p = s & (HW - 1);
    float att = att_a[s];
    int d = (s & ~(HW - 1)) | idx_a[s];
    int pos = atomicAdd(&cursor[d], 1);

    const float* xb = x + (size_t)b * C * HW + p;
    u32x4* row = rec + (size_t)pos * 8;
#pragma unroll
    for (int j = 0; j < 8; ++j) {
        float v0 = xb[(size_t)(j * 8 + 0) * HW] * att;
        float v1 = xb[(size_t)(j * 8 + 1) * HW] * att;
        float v2 = xb[(size_t)(j * 8 + 2) * HW] * att;
        float v3 = xb[(size_t)(j * 8 + 3) * HW] * att;
        float v4 = xb[(size_t)(j * 8 + 4) * HW] * att;
        float v5 = xb[(size_t)(j * 8 + 5) * HW] * att;
        float v6 = xb[(size_t)(j * 8 + 6) * HW] * att;
        float v7 = xb[(size_t)(j * 8 + 7) * HW] * att;
        u32x4 u;
        u.x = pack_bf16(v0, v1); u.y = pack_bf16(v2, v3);
        u.z = pack_bf16(v4, v5); u.w = pack_bf16(v6, v7);
        __builtin_nontemporal_store(u, row + j);   // full 128B line, bypass L2
    }
    __builtin_nontemporal_store(att, att_s + pos);
}

__global__ __launch_bounds__(256) void gather_kernel(
    const u32x4* __restrict__ rec, const float* __restrict__ att_s,
    const int* __restrict__ count, const int* __restrict__ base,
    float* __restrict__ out, int* __restrict__ heavy, int* __restrict__ heavy_n)
{
    int d = blockIdx.x * 256 + threadIdx.x;
    int k = count[d];
    if (k > KT) {
        heavy[atomicAdd(heavy_n, 1)] = d;
        return;
    }
    float acc[C];
#pragma unroll
    for (int c = 0; c < C; ++c) acc[c] = 0.f;
    float asum = 0.f;
    int st = base[d];
    for (int i = 0; i < k; ++i) {
        asum += __builtin_nontemporal_load(att_s + st + i);
        const u32x4* row = rec + (size_t)(st + i) * 8;   // sequential records
#pragma unroll
        for (int j = 0; j < 8; ++j) {
            u32x4 v = __builtin_nontemporal_load(row + j);
            acc[j * 8 + 0] += bf16_lo(v.x); acc[j * 8 + 1] += bf16_hi(v.x);
            acc[j * 8 + 2] += bf16_lo(v.y); acc[j * 8 + 3] += bf16_hi(v.y);
            acc[j * 8 + 4] += bf16_lo(v.z); acc[j * 8 + 5] += bf16_hi(v.z);
            acc[j * 8 + 6] += bf16_lo(v.w); acc[j * 8 + 7] += bf16_hi(v.w);
        }
    }
    float rinv = 1.0f / (EPS + asum);
    int b = d >> 18, p = d & (HW - 1);
    float* op = out + (size_t)b * C * HW + p;
#pragma unroll
    for (int c = 0; c < C; ++c)
        __builtin_nontemporal_store(acc[c] * rinv, op + (size_t)c * HW);
}

// one WAVE per heavy destination; 8 records (1KB) per wave-iteration
__global__ __launch_bounds__(256) void heavy_kernel(
    const u32x4* __restrict__ rec, const float* __restrict__ att_s,
    const int* __restrict__ count, const int* __restrict__ base,
    float* __restrict__ out,
    const int* __restrict__ heavy, const int* __restrict__ heavy_n)
{
    int nh = *heavy_n;
    int gw = (blockIdx.x * 256 + threadIdx.x) >> 6;   // global wave id
    int lane = threadIdx.x & 63;
    int nwaves = gridDim.x * 4;
    int rgrp = lane >> 3;                 // record-in-group 0..7

    for (int hi = gw; hi < nh; hi += nwaves) {
        int d = heavy[hi];
        int k = count[d], st = base[d];

        float asum = 0.f;
        for (int i = lane; i < k; i += 64) asum += att_s[st + i];
#pragma unroll
        for (int m = 32; m; m >>= 1) asum += __shfl_xor(asum, m, 64);

        float acc[8];
#pragma unroll
        for (int j = 0; j < 8; ++j) acc[j] = 0.f;
        const u32x4* rp = rec + (size_t)st * 8 + lane;
        int nit = (k + 7) >> 3;
        for (int it = 0; it < nit; ++it) {
            int r = it * 8 + rgrp;
            if (r < k) {
                u32x4 v = __builtin_nontemporal_load(rp + (size_t)it * 64);
                acc[0] += bf16_lo(v.x); acc[1] += bf16_hi(v.x);
                acc[2] += bf16_lo(v.y); acc[3] += bf16_hi(v.y);
                acc[4] += bf16_lo(v.z); acc[5] += bf16_hi(v.z);
                acc[6] += bf16_lo(v.w); acc[7] += bf16_hi(v.w);
            }
        }
#pragma unroll
        for (int m = 8; m < 64; m <<= 1) {
#pragma unroll
            for (int j = 0; j < 8; ++j) acc[j] += __shfl_xor(acc[j], m, 64);
        }
        if (lane < 8) {                   // lane writes channels lane*8..+7
            float rinv = 1.0f / (EPS + asum);
            int b = d >> 18, p = d & (HW - 1);
            float* op = out + (size_t)b * C * HW + (size_t)(lane * 8) * HW + p;
#pragma unroll
            for (int j = 0; j < 8; ++j) op[(size_t)j * HW] = acc[j] * rinv;
        }
    }
}

// ---------------- fallback path (R1, needs only 4 MB ws) ----------------

__global__ __launch_bounds__(256) void init_aa_kernel(float* __restrict__ aa) {
    int i = blockIdx.x * 256 + threadIdx.x;
    aa[i] = EPS;
}

__global__ __launch_bounds__(256) void conv_scatter_kernel(
    const float* __restrict__ x, const float* __restrict__ wmat,
    const float* __restrict__ bias, float* __restrict__ out,
    float* __restrict__ offset, float* __restrict__ dest,
    float* __restrict__ aa)
{
    __shared__ float wsh[3 * C];
    int t = threadIdx.x;
    if (t < 3 * C) wsh[t] = wmat[t];
    __syncthreads();

    int gid = blockIdx.x * 256 + t;
    int b = gid >> 18;
    int p = gid & (HW - 1);
    int hh = p >> 9, ww = p & (W - 1);

    const float* xb = x + (size_t)b * C * HW + p;
    float xv[C];
    float acc0 = 0.f, acc1 = 0.f, acc2 = 0.f;
#pragma unroll
    for (int c = 0; c < C; ++c) {
        float v = xb[(size_t)c * HW];
        xv[c] = v;
        acc0 = fmaf(v, wsh[c], acc0);
        acc1 = fmaf(v, wsh[C + c], acc1);
        acc2 = fmaf(v, wsh[2 * C + c], acc2);
    }
    acc0 += bias[0]; acc1 += bias[1]; acc2 += bias[2];

    float off_y = acc0 * (float)H;
    float off_x = acc1 * (float)W;
    float att = expf(acc2);

    int dy = (int)rintf((float)hh + off_y);
    dy = min(max(dy, 0), H - 1);
    int dx = (int)rintf((float)ww + off_x);
    dx = min(max(dx, 0), W - 1);
    int idx = dy * W + dx;

    size_t ob = (size_t)b * 2 * HW;
    offset[ob + p]      = off_y;
    offset[ob + HW + p] = off_x;
    dest[ob + p]      = (float)dy;
    dest[ob + HW + p] = (float)dx;

    atomicAdd(&aa[b * HW + idx], att);
    float* outp = out + (size_t)b * C * HW + idx;
#pragma unroll
    for (int c = 0; c < C; ++c) {
        atomicAdd(&outp[(size_t)c * HW], xv[c] * att);
    }
}

__global__ __launch_bounds__(256) void normalize_kernel(
    float* __restrict__ out, const float* __restrict__ aa)
{
    int i4 = blockIdx.x * 256 + threadIdx.x;
    size_t e = (size_t)i4 * 4;
    int b = (int)(e / ((size_t)C * HW));
    int p = (int)(e & (size_t)(HW - 1));
    float4 v = *reinterpret_cast<float4*>(out + e);
    const float4 a = *reinterpret_cast<const float4*>(aa + (size_t)b * HW + p);
    v.x /= a.x; v.y /= a.y; v.z /= a.z; v.w /= a.w;
    *reinterpret_cast<float4*>(out + e) = v;
}
} // namespace

extern "C" void kernel_launch(void* const* d_in, const int* in_sizes, int n_in,
                              void* d_out, int out_size, void* d_ws, size_t ws_size,
                              hipStream_t stream) {
    const float* x    = (const float*)d_in[0];
    const float* wmat = (const float*)d_in[1];
    const float* bias = (const float*)d_in[2];

    float* out    = (float*)d_out;                    // [B,C,H,W]
    float* offset = out + (size_t)B * C * HW;         // [B,2,H,W]
    float* dest   = offset + (size_t)B * 2 * HW;      // [B,2,H,W]

    // ws layout (~152.3 MB)
    char* w0 = (char*)d_ws;
    u32x4* rec   = (u32x4*)w0;                                  // 128 MB sorted records
    float* att_a = (float*)(w0 + (size_t)ND * 128);             // 4 MB
    float* att_s = (float*)((char*)att_a + (size_t)ND * 4);     // 4 MB sorted att
    int*   idx_a = (int*)((char*)att_s + (size_t)ND * 4);       // 4 MB
    int*   count = (int*)((char*)idx_a + (size_t)ND * 4);       // 4 MB
    int*   ctrs  = (int*)((char*)count + (size_t)ND * 4);       // [alloc, heavy_n]
    int*   base  = (int*)((char*)ctrs + 256);                   // 4 MB
    int*   cursor= (int*)((char*)base + (size_t)ND * 4);        // 4 MB
    int*   heavy = (int*)((char*)cursor + (size_t)ND * 4);      // 256 KB
    size_t need  = (size_t)(((char*)heavy + HEAVY_CAP * 4) - w0);

    if (ws_size >= need) {
        hipMemsetAsync(count, 0, (size_t)ND * 4 + 256, stream);  // count + ctrs
        conv_kernel<<<ND / 1024, 256, 0, stream>>>(
            x, wmat, bias, att_a, idx_a, count, offset, dest);
        scan_alloc_kernel<<<ND / 256, 256, 0, stream>>>(count, base, cursor, &ctrs[0]);
        sortcopy_kernel<<<ND / 256, 256, 0, stream>>>(
            x, att_a, idx_a, cursor, rec, att_s);
        gather_kernel<<<ND / 256, 256, 0, stream>>>(
            rec, att_s, count, base, out, heavy, &ctrs[1]);
        heavy_kernel<<<4096, 256, 0, stream>>>(
            rec, att_s, count, base, out, heavy, &ctrs[1]);
    } else {
        // fallback: R1 path (4 MB ws)
        float* aa = (float*)d_ws;
        hipMemsetAsync(out, 0, (size_t)B * C * HW * sizeof(float), stream);
        init_aa_kernel<<<B * HW / 256, 256, 0, stream>>>(aa);
        conv_scatter_kernel<<<B * HW / 256, 256, 0, stream>>>(
            x, wmat, bias, out, offset, dest, aa);
        normalize_kernel<<<(B * (size_t)C * HW / 4) / 256, 256, 0, stream>>>(out, aa);
    }
}

// Round 7
// 628.663 us; speedup vs baseline: 1.2254x; 1.2254x over previous
//
#include <hip/hip_runtime.h>

namespace {
constexpr int B = 4, C = 64, H = 512, W = 512;
constexpr int HW = H * W;                 // 2^18
constexpr int ND = B * HW;                // 2^20 sources == destinations
constexpr float EPS = 1e-5f;
constexpr int KT = 16;                    // heavy-destination threshold
constexpr int HEAVY_CAP = 65536;          // >= ND/(KT+1) = 61680, pigeonhole-safe

using u32x4 = __attribute__((ext_vector_type(4))) unsigned int;
using f32x4 = __attribute__((ext_vector_type(4))) float;
using i32x4 = __attribute__((ext_vector_type(4))) int;

__device__ __forceinline__ float bf16_lo(unsigned int u) {
    return __uint_as_float(u << 16);
}
__device__ __forceinline__ float bf16_hi(unsigned int u) {
    return __uint_as_float(u & 0xffff0000u);
}
__device__ __forceinline__ unsigned int pack_bf16(float a, float b) {
    unsigned int ua = __float_as_uint(a), ub = __float_as_uint(b);
    ua = (ua + 0x7fffu + ((ua >> 16) & 1u)) >> 16;   // RNE f32->bf16
    ub = (ub + 0x7fffu + ((ub >> 16) & 1u)) >> 16;
    return ua | (ub << 16);
}

// ---------------- fast path: sort records, then stream-gather --------------

// 4 pixels per thread, float4 x-loads; also accumulates the denominator aa
__global__ __launch_bounds__(256) void conv_kernel(
    const float* __restrict__ x, const float* __restrict__ wmat,
    const float* __restrict__ bias,
    float* __restrict__ att_a, int* __restrict__ idx_a,
    int* __restrict__ count, float* __restrict__ aa,
    float* __restrict__ offset, float* __restrict__ dest)
{
    __shared__ float wsh[3 * C];
    int t = threadIdx.x;
    if (t < 3 * C) wsh[t] = wmat[t];
    __syncthreads();

    int s0 = (blockIdx.x * 256 + t) * 4;  // first of 4 consecutive sources
    int b = s0 >> 18;
    int p0 = s0 & (HW - 1);
    int hh = p0 >> 9, ww = p0 & (W - 1);  // 4|W so all 4 share the row

    const float* xb = x + (size_t)b * C * HW + p0;
    float a0[4] = {0.f, 0.f, 0.f, 0.f};
    float a1[4] = {0.f, 0.f, 0.f, 0.f};
    float a2[4] = {0.f, 0.f, 0.f, 0.f};
#pragma unroll
    for (int c = 0; c < C; ++c) {
        f32x4 v = *reinterpret_cast<const f32x4*>(xb + (size_t)c * HW);
        float w0 = wsh[c], w1 = wsh[C + c], w2 = wsh[2 * C + c];
#pragma unroll
        for (int j = 0; j < 4; ++j) {
            a0[j] = fmaf(v[j], w0, a0[j]);
            a1[j] = fmaf(v[j], w1, a1[j]);
            a2[j] = fmaf(v[j], w2, a2[j]);
        }
    }
    float b0 = bias[0], b1 = bias[1], b2 = bias[2];

    f32x4 offy, offx, attv, dyv, dxv;
    i32x4 idxv;
#pragma unroll
    for (int j = 0; j < 4; ++j) {
        float oy = (a0[j] + b0) * (float)H;    // DOWNSAMPLE = 1.0
        float ox = (a1[j] + b1) * (float)W;
        float at = expf(a2[j] + b2);
        int dy = (int)rintf((float)hh + oy);   // RNE == jnp.round
        dy = min(max(dy, 0), H - 1);
        int dx = (int)rintf((float)(ww + j) + ox);
        dx = min(max(dx, 0), W - 1);
        offy[j] = oy; offx[j] = ox; attv[j] = at;
        dyv[j] = (float)dy; dxv[j] = (float)dx;
        idxv[j] = dy * W + dx;
        int di = (b << 18) | idxv[j];
        atomicAdd(&count[di], 1);
        atomicAdd(&aa[di], at);               // denominator: L2-resident 4MB
    }
    size_t ob = (size_t)b * 2 * HW;
    *reinterpret_cast<f32x4*>(offset + ob + p0)      = offy;
    *reinterpret_cast<f32x4*>(offset + ob + HW + p0) = offx;
    *reinterpret_cast<f32x4*>(dest + ob + p0)        = dyv;
    *reinterpret_cast<f32x4*>(dest + ob + HW + p0)   = dxv;
    *reinterpret_cast<f32x4*>(att_a + s0)            = attv;
    *reinterpret_cast<i32x4*>(idx_a + s0)            = idxv;
}

__global__ __launch_bounds__(256) void scan_alloc_kernel(
    const int* __restrict__ count, int* __restrict__ base,
    int* __restrict__ cursor, int* __restrict__ alloc)
{
    __shared__ int sd[256];
    __shared__ int blockBase;
    int t = threadIdx.x;
    int i = blockIdx.x * 256 + t;
    int c = count[i];
    sd[t] = c;
    __syncthreads();
#pragma unroll
    for (int off = 1; off < 256; off <<= 1) {     // Hillis-Steele inclusive
        int v = (t >= off) ? sd[t - off] : 0;
        __syncthreads();
        sd[t] += v;
        __syncthreads();
    }
    if (t == 255) blockBase = atomicAdd(alloc, sd[255]);
    __syncthreads();
    int bb = blockBase + sd[t] - c;
    base[i] = bb;
    cursor[i] = bb;
}

// re-read x, premultiply, write bf16 record into its sorted CSR slot
__global__ __launch_bounds__(256) void sortcopy_kernel(
    const float* __restrict__ x, const float* __restrict__ att_a,
    const int* __restrict__ idx_a, int* __restrict__ cursor,
    u32x4* __restrict__ rec)
{
    int s = blockIdx.x * 256 + threadIdx.x;
    int b = s >> 18;
    int p = s & (HW - 1);
    float att = att_a[s];
    int d = (s & ~(HW - 1)) | idx_a[s];
    int pos = atomicAdd(&cursor[d], 1);

    const float* xb = x + (size_t)b * C * HW + p;
    u32x4* row = rec + (size_t)pos * 8;
#pragma unroll
    for (int j = 0; j < 8; ++j) {
        float v0 = xb[(size_t)(j * 8 + 0) * HW] * att;
        float v1 = xb[(size_t)(j * 8 + 1) * HW] * att;
        float v2 = xb[(size_t)(j * 8 + 2) * HW] * att;
        float v3 = xb[(size_t)(j * 8 + 3) * HW] * att;
        float v4 = xb[(size_t)(j * 8 + 4) * HW] * att;
        float v5 = xb[(size_t)(j * 8 + 5) * HW] * att;
        float v6 = xb[(size_t)(j * 8 + 6) * HW] * att;
        float v7 = xb[(size_t)(j * 8 + 7) * HW] * att;
        u32x4 u;
        u.x = pack_bf16(v0, v1); u.y = pack_bf16(v2, v3);
        u.z = pack_bf16(v4, v5); u.w = pack_bf16(v6, v7);
        row[j] = u;                       // 128B contiguous full-line record
    }
}

__global__ __launch_bounds__(256) void gather_kernel(
    const u32x4* __restrict__ rec, const float* __restrict__ aa,
    const int* __restrict__ count, const int* __restrict__ base,
    float* __restrict__ out, int* __restrict__ heavy, int* __restrict__ heavy_n)
{
    int d = blockIdx.x * 256 + threadIdx.x;
    int k = count[d];
    if (k > KT) {
        heavy[atomicAdd(heavy_n, 1)] = d;
        return;
    }
    float acc[C];
#pragma unroll
    for (int c = 0; c < C; ++c) acc[c] = 0.f;
    int st = base[d];
    for (int i = 0; i < k; ++i) {
        const u32x4* row = rec + (size_t)(st + i) * 8;   // sequential records
#pragma unroll
        for (int j = 0; j < 8; ++j) {
            u32x4 v = __builtin_nontemporal_load(row + j);
            acc[j * 8 + 0] += bf16_lo(v.x); acc[j * 8 + 1] += bf16_hi(v.x);
            acc[j * 8 + 2] += bf16_lo(v.y); acc[j * 8 + 3] += bf16_hi(v.y);
            acc[j * 8 + 4] += bf16_lo(v.z); acc[j * 8 + 5] += bf16_hi(v.z);
            acc[j * 8 + 6] += bf16_lo(v.w); acc[j * 8 + 7] += bf16_hi(v.w);
        }
    }
    float rinv = 1.0f / (EPS + aa[d]);
    int b = d >> 18, p = d & (HW - 1);
    float* op = out + (size_t)b * C * HW + p;
#pragma unroll
    for (int c = 0; c < C; ++c) op[(size_t)c * HW] = acc[c] * rinv;  // coalesced
}

// one WAVE per heavy destination; 8 records (1KB) per wave-iteration
__global__ __launch_bounds__(256) void heavy_kernel(
    const u32x4* __restrict__ rec, const float* __restrict__ aa,
    const int* __restrict__ count, const int* __restrict__ base,
    float* __restrict__ out,
    const int* __restrict__ heavy, const int* __restrict__ heavy_n)
{
    int nh = *heavy_n;
    int gw = (blockIdx.x * 256 + threadIdx.x) >> 6;   // global wave id
    int lane = threadIdx.x & 63;
    int nwaves = gridDim.x * 4;
    int rgrp = lane >> 3;                 // record-in-group 0..7

    for (int hi = gw; hi < nh; hi += nwaves) {
        int d = heavy[hi];
        int k = count[d], st = base[d];

        float acc[8];
#pragma unroll
        for (int j = 0; j < 8; ++j) acc[j] = 0.f;
        const u32x4* rp = rec + (size_t)st * 8 + lane;
        int nit = (k + 7) >> 3;
        for (int it = 0; it < nit; ++it) {
            int r = it * 8 + rgrp;
            if (r < k) {
                u32x4 v = __builtin_nontemporal_load(rp + (size_t)it * 64);
                acc[0] += bf16_lo(v.x); acc[1] += bf16_hi(v.x);
                acc[2] += bf16_lo(v.y); acc[3] += bf16_hi(v.y);
                acc[4] += bf16_lo(v.z); acc[5] += bf16_hi(v.z);
                acc[6] += bf16_lo(v.w); acc[7] += bf16_hi(v.w);
            }
        }
#pragma unroll
        for (int m = 8; m < 64; m <<= 1) {
#pragma unroll
            for (int j = 0; j < 8; ++j) acc[j] += __shfl_xor(acc[j], m, 64);
        }
        if (lane < 8) {                   // lane writes channels lane*8..+7
            float rinv = 1.0f / (EPS + aa[d]);
            int b = d >> 18, p = d & (HW - 1);
            float* op = out + (size_t)b * C * HW + (size_t)(lane * 8) * HW + p;
#pragma unroll
            for (int j = 0; j < 8; ++j) op[(size_t)j * HW] = acc[j] * rinv;
        }
    }
}

// ---------------- fallback path (R1, needs only 4 MB ws) ----------------

__global__ __launch_bounds__(256) void init_aa_kernel(float* __restrict__ aa) {
    int i = blockIdx.x * 256 + threadIdx.x;
    aa[i] = EPS;
}

__global__ __launch_bounds__(256) void conv_scatter_kernel(
    const float* __restrict__ x, const float* __restrict__ wmat,
    const float* __restrict__ bias, float* __restrict__ out,
    float* __restrict__ offset, float* __restrict__ dest,
    float* __restrict__ aa)
{
    __shared__ float wsh[3 * C];
    int t = threadIdx.x;
    if (t < 3 * C) wsh[t] = wmat[t];
    __syncthreads();

    int gid = blockIdx.x * 256 + t;
    int b = gid >> 18;
    int p = gid & (HW - 1);
    int hh = p >> 9, ww = p & (W - 1);

    const float* xb = x + (size_t)b * C * HW + p;
    float xv[C];
    float acc0 = 0.f, acc1 = 0.f, acc2 = 0.f;
#pragma unroll
    for (int c = 0; c < C; ++c) {
        float v = xb[(size_t)c * HW];
        xv[c] = v;
        acc0 = fmaf(v, wsh[c], acc0);
        acc1 = fmaf(v, wsh[C + c], acc1);
        acc2 = fmaf(v, wsh[2 * C + c], acc2);
    }
    acc0 += bias[0]; acc1 += bias[1]; acc2 += bias[2];

    float off_y = acc0 * (float)H;
    float off_x = acc1 * (float)W;
    float att = expf(acc2);

    int dy = (int)rintf((float)hh + off_y);
    dy = min(max(dy, 0), H - 1);
    int dx = (int)rintf((float)ww + off_x);
    dx = min(max(dx, 0), W - 1);
    int idx = dy * W + dx;

    size_t ob = (size_t)b * 2 * HW;
    offset[ob + p]      = off_y;
    offset[ob + HW + p] = off_x;
    dest[ob + p]      = (float)dy;
    dest[ob + HW + p] = (float)dx;

    atomicAdd(&aa[b * HW + idx], att);
    float* outp = out + (size_t)b * C * HW + idx;
#pragma unroll
    for (int c = 0; c < C; ++c) {
        atomicAdd(&outp[(size_t)c * HW], xv[c] * att);
    }
}

__global__ __launch_bounds__(256) void normalize_kernel(
    float* __restrict__ out, const float* __restrict__ aa)
{
    int i4 = blockIdx.x * 256 + threadIdx.x;
    size_t e = (size_t)i4 * 4;
    int b = (int)(e / ((size_t)C * HW));
    int p = (int)(e & (size_t)(HW - 1));
    float4 v = *reinterpret_cast<float4*>(out + e);
    const float4 a = *reinterpret_cast<const float4*>(aa + (size_t)b * HW + p);
    v.x /= a.x; v.y /= a.y; v.z /= a.z; v.w /= a.w;
    *reinterpret_cast<float4*>(out + e) = v;
}
} // namespace

extern "C" void kernel_launch(void* const* d_in, const int* in_sizes, int n_in,
                              void* d_out, int out_size, void* d_ws, size_t ws_size,
                              hipStream_t stream) {
    const float* x    = (const float*)d_in[0];
    const float* wmat = (const float*)d_in[1];
    const float* bias = (const float*)d_in[2];

    float* out    = (float*)d_out;                    // [B,C,H,W]
    float* offset = out + (size_t)B * C * HW;         // [B,2,H,W]
    float* dest   = offset + (size_t)B * 2 * HW;      // [B,2,H,W]

    // ws layout (~152.3 MB)
    char* w0 = (char*)d_ws;
    u32x4* rec   = (u32x4*)w0;                                  // 128 MB sorted records
    float* att_a = (float*)(w0 + (size_t)ND * 128);             // 4 MB
    int*   idx_a = (int*)((char*)att_a + (size_t)ND * 4);       // 4 MB
    float* aa    = (float*)((char*)idx_a + (size_t)ND * 4);     // 4 MB (zeroed)
    int*   count = (int*)((char*)aa + (size_t)ND * 4);          // 4 MB (zeroed)
    int*   ctrs  = (int*)((char*)count + (size_t)ND * 4);       // [alloc, heavy_n] (zeroed)
    int*   base  = (int*)((char*)ctrs + 256);                   // 4 MB
    int*   cursor= (int*)((char*)base + (size_t)ND * 4);        // 4 MB
    int*   heavy = (int*)((char*)cursor + (size_t)ND * 4);      // 256 KB
    size_t need  = (size_t)(((char*)heavy + HEAVY_CAP * 4) - w0);

    if (ws_size >= need) {
        hipMemsetAsync(aa, 0, (size_t)ND * 8 + 256, stream);    // aa + count + ctrs
        conv_kernel<<<ND / 1024, 256, 0, stream>>>(
            x, wmat, bias, att_a, idx_a, count, aa, offset, dest);
        scan_alloc_kernel<<<ND / 256, 256, 0, stream>>>(count, base, cursor, &ctrs[0]);
        sortcopy_kernel<<<ND / 256, 256, 0, stream>>>(
            x, att_a, idx_a, cursor, rec);
        gather_kernel<<<ND / 256, 256, 0, stream>>>(
            rec, aa, count, base, out, heavy, &ctrs[1]);
        heavy_kernel<<<4096, 256, 0, stream>>>(
            rec, aa, count, base, out, heavy, &ctrs[1]);
    } else {
        // fallback: R1 path (4 MB ws)
        float* aaf = (float*)d_ws;
        hipMemsetAsync(out, 0, (size_t)B * C * HW * sizeof(float), stream);
        init_aa_kernel<<<B * HW / 256, 256, 0, stream>>>(aaf);
        conv_scatter_kernel<<<B * HW / 256, 256, 0, stream>>>(
            x, wmat, bias, out, offset, dest, aaf);
        normalize_kernel<<<(B * (size_t)C * HW / 4) / 256, 256, 0, stream>>>(out, aaf);
    }
}

// Round 8
// 560.930 us; speedup vs baseline: 1.3733x; 1.1208x over previous
//
#include <hip/hip_runtime.h>

namespace {
constexpr int B = 4, C = 64, H = 512, W = 512;
constexpr int HW = H * W;                 // 2^18
constexpr int ND = B * HW;                // 2^20 sources == destinations
constexpr float EPS = 1e-5f;
constexpr int KT = 16;                    // heavy-destination threshold
constexpr int HEAVY_CAP = 65536;          // >= ND/(KT+1) = 61680, pigeonhole-safe

// packed per-destination accumulator: bits [43..63] = count, [0..42] = Q22.21 sum(att)
constexpr int PSHIFT = 43;
constexpr float PSCALE = 2097152.0f;      // 2^21
constexpr float PINV   = 1.0f / 2097152.0f;
constexpr unsigned long long PMASK = ((1ull << PSHIFT) - 1);

using u32x4 = __attribute__((ext_vector_type(4))) unsigned int;
using f32x4 = __attribute__((ext_vector_type(4))) float;

__device__ __forceinline__ float bf16_lo(unsigned int u) {
    return __uint_as_float(u << 16);
}
__device__ __forceinline__ float bf16_hi(unsigned int u) {
    return __uint_as_float(u & 0xffff0000u);
}
__device__ __forceinline__ unsigned int pack_bf16(float a, float b) {
    unsigned int ua = __float_as_uint(a), ub = __float_as_uint(b);
    ua = (ua + 0x7fffu + ((ua >> 16) & 1u)) >> 16;   // RNE f32->bf16
    ub = (ub + 0x7fffu + ((ub >> 16) & 1u)) >> 16;
    return ua | (ub << 16);
}

// ---------------- fast path ----------------
// conv: read x once, compute offsets/att, ONE packed atomic, write premultiplied
// bf16 record (unsorted) into the out-region scratch (dead until gather).
__global__ __launch_bounds__(256) void conv_kernel(
    const float* __restrict__ x, const float* __restrict__ wmat,
    const float* __restrict__ bias,
    int* __restrict__ idx_a, unsigned long long* __restrict__ packed,
    u32x4* __restrict__ rec_u,
    float* __restrict__ offset, float* __restrict__ dest)
{
    __shared__ float wsh[3 * C];
    int t = threadIdx.x;
    if (t < 3 * C) wsh[t] = wmat[t];
    __syncthreads();

    int s = blockIdx.x * 256 + t;         // source id (b<<18 | p)
    int b = s >> 18;
    int p = s & (HW - 1);
    int hh = p >> 9, ww = p & (W - 1);

    const float* xb = x + (size_t)b * C * HW + p;
    float xv[C];
    float acc0 = 0.f, acc1 = 0.f, acc2 = 0.f;
#pragma unroll
    for (int c = 0; c < C; ++c) {
        float v = xb[(size_t)c * HW];     // coalesced 256B/wave per c
        xv[c] = v;
        acc0 = fmaf(v, wsh[c], acc0);
        acc1 = fmaf(v, wsh[C + c], acc1);
        acc2 = fmaf(v, wsh[2 * C + c], acc2);
    }
    acc0 += bias[0]; acc1 += bias[1]; acc2 += bias[2];

    float oy = acc0 * (float)H;           // DOWNSAMPLE = 1.0
    float ox = acc1 * (float)W;
    float att = expf(acc2);

    int dy = (int)rintf((float)hh + oy);  // RNE == jnp.round
    dy = min(max(dy, 0), H - 1);
    int dx = (int)rintf((float)ww + ox);
    dx = min(max(dx, 0), W - 1);
    int idx = dy * W + dx;

    size_t ob = (size_t)b * 2 * HW;
    offset[ob + p]      = oy;
    offset[ob + HW + p] = ox;
    dest[ob + p]      = (float)dy;
    dest[ob + HW + p] = (float)dx;
    idx_a[s] = idx;

    int di = (b << 18) | idx;
    atomicAdd(&packed[di],
              (1ull << PSHIFT) | (unsigned long long)(att * PSCALE));

    // premultiplied bf16 record, 128B contiguous per source (coalesced 8KB/wave)
    u32x4* row = rec_u + (size_t)s * 8;
#pragma unroll
    for (int j = 0; j < 8; ++j) {
        u32x4 u;
        u.x = pack_bf16(xv[j * 8 + 0] * att, xv[j * 8 + 1] * att);
        u.y = pack_bf16(xv[j * 8 + 2] * att, xv[j * 8 + 3] * att);
        u.z = pack_bf16(xv[j * 8 + 4] * att, xv[j * 8 + 5] * att);
        u.w = pack_bf16(xv[j * 8 + 6] * att, xv[j * 8 + 7] * att);
        row[j] = u;
    }
}

__global__ __launch_bounds__(256) void scan_alloc_kernel(
    const unsigned long long* __restrict__ packed,
    int* __restrict__ cursor, int* __restrict__ alloc)
{
    __shared__ int sd[256];
    __shared__ int blockBase;
    int t = threadIdx.x;
    int i = blockIdx.x * 256 + t;
    int c = (int)(packed[i] >> PSHIFT);
    sd[t] = c;
    __syncthreads();
#pragma unroll
    for (int off = 1; off < 256; off <<= 1) {     // Hillis-Steele inclusive
        int v = (t >= off) ? sd[t - off] : 0;
        __syncthreads();
        sd[t] += v;
        __syncthreads();
    }
    if (t == 255) blockBase = atomicAdd(alloc, sd[255]);
    __syncthreads();
    cursor[i] = blockBase + sd[t] - c;            // exclusive start
}

// pure permutation copy: unsorted record -> sorted CSR slot (full-line writes)
__global__ __launch_bounds__(256) void sortcopy_kernel(
    const u32x4* __restrict__ rec_u, const int* __restrict__ idx_a,
    int* __restrict__ cursor, u32x4* __restrict__ rec)
{
    int s = blockIdx.x * 256 + threadIdx.x;
    int d = (s & ~(HW - 1)) | idx_a[s];
    int pos = atomicAdd(&cursor[d], 1);

    const u32x4* src = rec_u + (size_t)s * 8;     // sequential 128B read
    u32x4* dst = rec + (size_t)pos * 8;           // scattered full-line write
#pragma unroll
    for (int j = 0; j < 8; ++j) dst[j] = src[j];
}

__global__ __launch_bounds__(256) void gather_kernel(
    const u32x4* __restrict__ rec, const unsigned long long* __restrict__ packed,
    const int* __restrict__ cursor, float* __restrict__ out,
    int* __restrict__ heavy, int* __restrict__ heavy_n)
{
    int d = blockIdx.x * 256 + threadIdx.x;
    unsigned long long P = packed[d];
    int k = (int)(P >> PSHIFT);
    if (k > KT) {
        heavy[atomicAdd(heavy_n, 1)] = d;
        return;
    }
    float acc[C];
#pragma unroll
    for (int c = 0; c < C; ++c) acc[c] = 0.f;
    int st = cursor[d] - k;               // cursor is now the CSR end
    for (int i = 0; i < k; ++i) {
        const u32x4* row = rec + (size_t)(st + i) * 8;   // sequential records
#pragma unroll
        for (int j = 0; j < 8; ++j) {
            u32x4 v = __builtin_nontemporal_load(row + j);
            acc[j * 8 + 0] += bf16_lo(v.x); acc[j * 8 + 1] += bf16_hi(v.x);
            acc[j * 8 + 2] += bf16_lo(v.y); acc[j * 8 + 3] += bf16_hi(v.y);
            acc[j * 8 + 4] += bf16_lo(v.z); acc[j * 8 + 5] += bf16_hi(v.z);
            acc[j * 8 + 6] += bf16_lo(v.w); acc[j * 8 + 7] += bf16_hi(v.w);
        }
    }
    float asum = (float)(P & PMASK) * PINV;
    float rinv = 1.0f / (EPS + asum);
    int b = d >> 18, p = d & (HW - 1);
    float* op = out + (size_t)b * C * HW + p;
#pragma unroll
    for (int c = 0; c < C; ++c) op[(size_t)c * HW] = acc[c] * rinv;  // coalesced
}

// one WAVE per heavy destination; 8 records (1KB) per wave-iteration
__global__ __launch_bounds__(256) void heavy_kernel(
    const u32x4* __restrict__ rec, const unsigned long long* __restrict__ packed,
    const int* __restrict__ cursor, float* __restrict__ out,
    const int* __restrict__ heavy, const int* __restrict__ heavy_n)
{
    int nh = *heavy_n;
    int gw = (blockIdx.x * 256 + threadIdx.x) >> 6;   // global wave id
    int lane = threadIdx.x & 63;
    int nwaves = gridDim.x * 4;
    int rgrp = lane >> 3;                 // record-in-group 0..7

    for (int hi = gw; hi < nh; hi += nwaves) {
        int d = heavy[hi];
        unsigned long long P = packed[d];
        int k = (int)(P >> PSHIFT);
        int st = cursor[d] - k;

        float acc[8];
#pragma unroll
        for (int j = 0; j < 8; ++j) acc[j] = 0.f;
        const u32x4* rp = rec + (size_t)st * 8 + lane;
        int nit = (k + 7) >> 3;
        for (int it = 0; it < nit; ++it) {
            int r = it * 8 + rgrp;
            if (r < k) {
                u32x4 v = __builtin_nontemporal_load(rp + (size_t)it * 64);
                acc[0] += bf16_lo(v.x); acc[1] += bf16_hi(v.x);
                acc[2] += bf16_lo(v.y); acc[3] += bf16_hi(v.y);
                acc[4] += bf16_lo(v.z); acc[5] += bf16_hi(v.z);
                acc[6] += bf16_lo(v.w); acc[7] += bf16_hi(v.w);
            }
        }
#pragma unroll
        for (int m = 8; m < 64; m <<= 1) {
#pragma unroll
            for (int j = 0; j < 8; ++j) acc[j] += __shfl_xor(acc[j], m, 64);
        }
        if (lane < 8) {                   // lane writes channels lane*8..+7
            float asum = (float)(P & PMASK) * PINV;
            float rinv = 1.0f / (EPS + asum);
            int b = d >> 18, p = d & (HW - 1);
            float* op = out + (size_t)b * C * HW + (size_t)(lane * 8) * HW + p;
#pragma unroll
            for (int j = 0; j < 8; ++j) op[(size_t)j * HW] = acc[j] * rinv;
        }
    }
}

// ---------------- fallback path (R1, needs only 4 MB ws) ----------------

__global__ __launch_bounds__(256) void init_aa_kernel(float* __restrict__ aa) {
    int i = blockIdx.x * 256 + threadIdx.x;
    aa[i] = EPS;
}

__global__ __launch_bounds__(256) void conv_scatter_kernel(
    const float* __restrict__ x, const float* __restrict__ wmat,
    const float* __restrict__ bias, float* __restrict__ out,
    float* __restrict__ offset, float* __restrict__ dest,
    float* __restrict__ aa)
{
    __shared__ float wsh[3 * C];
    int t = threadIdx.x;
    if (t < 3 * C) wsh[t] = wmat[t];
    __syncthreads();

    int gid = blockIdx.x * 256 + t;
    int b = gid >> 18;
    int p = gid & (HW - 1);
    int hh = p >> 9, ww = p & (W - 1);

    const float* xb = x + (size_t)b * C * HW + p;
    float xv[C];
    float acc0 = 0.f, acc1 = 0.f, acc2 = 0.f;
#pragma unroll
    for (int c = 0; c < C; ++c) {
        float v = xb[(size_t)c * HW];
        xv[c] = v;
        acc0 = fmaf(v, wsh[c], acc0);
        acc1 = fmaf(v, wsh[C + c], acc1);
        acc2 = fmaf(v, wsh[2 * C + c], acc2);
    }
    acc0 += bias[0]; acc1 += bias[1]; acc2 += bias[2];

    float off_y = acc0 * (float)H;
    float off_x = acc1 * (float)W;
    float att = expf(acc2);

    int dy = (int)rintf((float)hh + off_y);
    dy = min(max(dy, 0), H - 1);
    int dx = (int)rintf((float)ww + off_x);
    dx = min(max(dx, 0), W - 1);
    int idx = dy * W + dx;

    size_t ob = (size_t)b * 2 * HW;
    offset[ob + p]      = off_y;
    offset[ob + HW + p] = off_x;
    dest[ob + p]      = (float)dy;
    dest[ob + HW + p] = (float)dx;

    atomicAdd(&aa[b * HW + idx], att);
    float* outp = out + (size_t)b * C * HW + idx;
#pragma unroll
    for (int c = 0; c < C; ++c) {
        atomicAdd(&outp[(size_t)c * HW], xv[c] * att);
    }
}

__global__ __launch_bounds__(256) void normalize_kernel(
    float* __restrict__ out, const float* __restrict__ aa)
{
    int i4 = blockIdx.x * 256 + threadIdx.x;
    size_t e = (size_t)i4 * 4;
    int b = (int)(e / ((size_t)C * HW));
    int p = (int)(e & (size_t)(HW - 1));
    float4 v = *reinterpret_cast<float4*>(out + e);
    const float4 a = *reinterpret_cast<const float4*>(aa + (size_t)b * HW + p);
    v.x /= a.x; v.y /= a.y; v.z /= a.z; v.w /= a.w;
    *reinterpret_cast<float4*>(out + e) = v;
}
} // namespace

extern "C" void kernel_launch(void* const* d_in, const int* in_sizes, int n_in,
                              void* d_out, int out_size, void* d_ws, size_t ws_size,
                              hipStream_t stream) {
    const float* x    = (const float*)d_in[0];
    const float* wmat = (const float*)d_in[1];
    const float* bias = (const float*)d_in[2];

    float* out    = (float*)d_out;                    // [B,C,H,W] (256 MB)
    float* offset = out + (size_t)B * C * HW;         // [B,2,H,W]
    float* dest   = offset + (size_t)B * 2 * HW;      // [B,2,H,W]

    // unsorted records live in the out-region scratch (first 128 MB, dead
    // until gather/heavy overwrite every element of out)
    u32x4* rec_u = (u32x4*)d_out;

    // ws layout (~144.3 MB)
    char* w0 = (char*)d_ws;
    u32x4* rec = (u32x4*)w0;                                        // 128 MB sorted
    int*   idx_a = (int*)(w0 + (size_t)ND * 128);                   // 4 MB
    unsigned long long* packed =
        (unsigned long long*)((char*)idx_a + (size_t)ND * 4);       // 8 MB (zeroed)
    int*   ctrs  = (int*)((char*)packed + (size_t)ND * 8);          // 256 B (zeroed)
    int*   cursor= (int*)((char*)ctrs + 256);                       // 4 MB
    int*   heavy = (int*)((char*)cursor + (size_t)ND * 4);          // 256 KB
    size_t need  = (size_t)(((char*)heavy + HEAVY_CAP * 4) - w0);

    if (ws_size >= need) {
        hipMemsetAsync(packed, 0, (size_t)ND * 8 + 256, stream);    // packed + ctrs
        conv_kernel<<<ND / 256, 256, 0, stream>>>(
            x, wmat, bias, idx_a, packed, rec_u, offset, dest);
        scan_alloc_kernel<<<ND / 256, 256, 0, stream>>>(packed, cursor, &ctrs[0]);
        sortcopy_kernel<<<ND / 256, 256, 0, stream>>>(rec_u, idx_a, cursor, rec);
        gather_kernel<<<ND / 256, 256, 0, stream>>>(
            rec, packed, cursor, out, heavy, &ctrs[1]);
        heavy_kernel<<<4096, 256, 0, stream>>>(
            rec, packed, cursor, out, heavy, &ctrs[1]);
    } else {
        // fallback: R1 path (4 MB ws)
        float* aaf = (float*)d_ws;
        hipMemsetAsync(out, 0, (size_t)B * C * HW * sizeof(float), stream);
        init_aa_kernel<<<B * HW / 256, 256, 0, stream>>>(aaf);
        conv_scatter_kernel<<<B * HW / 256, 256, 0, stream>>>(
            x, wmat, bias, out, offset, dest, aaf);
        normalize_kernel<<<(B * (size_t)C * HW / 4) / 256, 256, 0, stream>>>(out, aaf);
    }
}

// Round 9
// 542.829 us; speedup vs baseline: 1.4191x; 1.0333x over previous
//
#include <hip/hip_runtime.h>

namespace {
constexpr int B = 4, C = 64, H = 512, W = 512;
constexpr int HW = H * W;                 // 2^18
constexpr int ND = B * HW;                // 2^20 sources == destinations
constexpr float EPS = 1e-5f;
constexpr int KT = 16;                    // heavy-destination threshold
constexpr int HEAVY_CAP = 65536;          // >= ND/(KT+1) = 61680, pigeonhole-safe

// packed per-destination accumulator: bits [43..63] = count, [0..42] = Q22.21 sum(att)
constexpr int PSHIFT = 43;
constexpr float PSCALE = 2097152.0f;      // 2^21
constexpr float PINV   = 1.0f / 2097152.0f;
constexpr unsigned long long PMASK = ((1ull << PSHIFT) - 1);

using u32x4 = __attribute__((ext_vector_type(4))) unsigned int;

__device__ __forceinline__ float bf16_lo(unsigned int u) {
    return __uint_as_float(u << 16);
}
__device__ __forceinline__ float bf16_hi(unsigned int u) {
    return __uint_as_float(u & 0xffff0000u);
}
__device__ __forceinline__ unsigned int pack_bf16(float a, float b) {
    unsigned int ua = __float_as_uint(a), ub = __float_as_uint(b);
    ua = (ua + 0x7fffu + ((ua >> 16) & 1u)) >> 16;   // RNE f32->bf16
    ub = (ub + 0x7fffu + ((ub >> 16) & 1u)) >> 16;
    return ua | (ub << 16);
}

// ---------------- fast path ----------------
// conv: read x once (nt), compute offsets/att, ONE packed atomic, write
// premultiplied bf16 record (unsorted) into the out-region scratch.
__global__ __launch_bounds__(256) void conv_kernel(
    const float* __restrict__ x, const float* __restrict__ wmat,
    const float* __restrict__ bias,
    int* __restrict__ idx_a, unsigned long long* __restrict__ packed,
    u32x4* __restrict__ rec_u,
    float* __restrict__ offset, float* __restrict__ dest)
{
    __shared__ float wsh[3 * C];
    int t = threadIdx.x;
    if (t < 3 * C) wsh[t] = wmat[t];
    __syncthreads();

    int s = blockIdx.x * 256 + t;         // source id (b<<18 | p)
    int b = s >> 18;
    int p = s & (HW - 1);
    int hh = p >> 9, ww = p & (W - 1);

    const float* xb = x + (size_t)b * C * HW + p;
    float xv[C];
    float acc0 = 0.f, acc1 = 0.f, acc2 = 0.f;
#pragma unroll
    for (int c = 0; c < C; ++c) {
        float v = __builtin_nontemporal_load(xb + (size_t)c * HW);  // read-once
        xv[c] = v;
        acc0 = fmaf(v, wsh[c], acc0);
        acc1 = fmaf(v, wsh[C + c], acc1);
        acc2 = fmaf(v, wsh[2 * C + c], acc2);
    }
    acc0 += bias[0]; acc1 += bias[1]; acc2 += bias[2];

    float oy = acc0 * (float)H;           // DOWNSAMPLE = 1.0
    float ox = acc1 * (float)W;
    float att = expf(acc2);

    int dy = (int)rintf((float)hh + oy);  // RNE == jnp.round
    dy = min(max(dy, 0), H - 1);
    int dx = (int)rintf((float)ww + ox);
    dx = min(max(dx, 0), W - 1);
    int idx = dy * W + dx;

    size_t ob = (size_t)b * 2 * HW;
    offset[ob + p]      = oy;
    offset[ob + HW + p] = ox;
    dest[ob + p]      = (float)dy;
    dest[ob + HW + p] = (float)dx;
    idx_a[s] = idx;

    int di = (b << 18) | idx;
    atomicAdd(&packed[di],
              (1ull << PSHIFT) | (unsigned long long)(att * PSCALE));

    // premultiplied bf16 record, 128B contiguous per source (coalesced 8KB/wave)
    u32x4* row = rec_u + (size_t)s * 8;
#pragma unroll
    for (int j = 0; j < 8; ++j) {
        u32x4 u;
        u.x = pack_bf16(xv[j * 8 + 0] * att, xv[j * 8 + 1] * att);
        u.y = pack_bf16(xv[j * 8 + 2] * att, xv[j * 8 + 3] * att);
        u.z = pack_bf16(xv[j * 8 + 4] * att, xv[j * 8 + 5] * att);
        u.w = pack_bf16(xv[j * 8 + 6] * att, xv[j * 8 + 7] * att);
        row[j] = u;                       // normal stores: L2 assembles full lines
    }
}

__global__ __launch_bounds__(256) void scan_alloc_kernel(
    const unsigned long long* __restrict__ packed,
    int* __restrict__ cursor, int* __restrict__ alloc)
{
    __shared__ int sd[256];
    __shared__ int blockBase;
    int t = threadIdx.x;
    int i = blockIdx.x * 256 + t;
    int c = (int)(packed[i] >> PSHIFT);
    sd[t] = c;
    __syncthreads();
#pragma unroll
    for (int off = 1; off < 256; off <<= 1) {     // Hillis-Steele inclusive
        int v = (t >= off) ? sd[t - off] : 0;
        __syncthreads();
        sd[t] += v;
        __syncthreads();
    }
    if (t == 255) blockBase = atomicAdd(alloc, sd[255]);
    __syncthreads();
    cursor[i] = blockBase + sd[t] - c;            // exclusive start
}

// pure permutation copy: unsorted record -> sorted CSR slot (full-line writes)
__global__ __launch_bounds__(256) void sortcopy_kernel(
    const u32x4* __restrict__ rec_u, const int* __restrict__ idx_a,
    int* __restrict__ cursor, u32x4* __restrict__ rec)
{
    int s = blockIdx.x * 256 + threadIdx.x;
    int d = (s & ~(HW - 1)) | idx_a[s];
    int pos = atomicAdd(&cursor[d], 1);

    const u32x4* src = rec_u + (size_t)s * 8;     // sequential 128B read (once)
    u32x4* dst = rec + (size_t)pos * 8;           // scattered full-line write
#pragma unroll
    for (int j = 0; j < 8; ++j)
        dst[j] = __builtin_nontemporal_load(src + j);
}

// 2 threads per destination: h = channel half (32 channels each)
__global__ __launch_bounds__(256) void gather_kernel(
    const u32x4* __restrict__ rec, const unsigned long long* __restrict__ packed,
    const int* __restrict__ cursor, float* __restrict__ out,
    int* __restrict__ heavy, int* __restrict__ heavy_n)
{
    int tid = blockIdx.x * 256 + threadIdx.x;
    int d = tid >> 1, h = tid & 1;
    unsigned long long P = packed[d];
    int k = (int)(P >> PSHIFT);
    if (k > KT) {
        if (h == 0) heavy[atomicAdd(heavy_n, 1)] = d;
        return;
    }
    float acc[32];
#pragma unroll
    for (int c = 0; c < 32; ++c) acc[c] = 0.f;
    int st = cursor[d] - k;               // cursor is the CSR end
    const u32x4* rbase = rec + (size_t)st * 8 + h * 4;   // this half's 64B
    for (int i = 0; i < k; ++i) {
#pragma unroll
        for (int j = 0; j < 4; ++j) {
            u32x4 v = __builtin_nontemporal_load(rbase + (size_t)i * 8 + j);
            acc[j * 8 + 0] += bf16_lo(v.x); acc[j * 8 + 1] += bf16_hi(v.x);
            acc[j * 8 + 2] += bf16_lo(v.y); acc[j * 8 + 3] += bf16_hi(v.y);
            acc[j * 8 + 4] += bf16_lo(v.z); acc[j * 8 + 5] += bf16_hi(v.z);
            acc[j * 8 + 6] += bf16_lo(v.w); acc[j * 8 + 7] += bf16_hi(v.w);
        }
    }
    float asum = (float)(P & PMASK) * PINV;
    float rinv = 1.0f / (EPS + asum);
    int b = d >> 18, p = d & (HW - 1);
    float* op = out + (size_t)b * C * HW + (size_t)(h * 32) * HW + p;
#pragma unroll
    for (int c = 0; c < 32; ++c) op[(size_t)c * HW] = acc[c] * rinv;  // 2 full lines/instr
}

// one WAVE per heavy destination; 8 records (1KB) per wave-iteration
__global__ __launch_bounds__(256) void heavy_kernel(
    const u32x4* __restrict__ rec, const unsigned long long* __restrict__ packed,
    const int* __restrict__ cursor, float* __restrict__ out,
    const int* __restrict__ heavy, const int* __restrict__ heavy_n)
{
    int nh = *heavy_n;
    int gw = (blockIdx.x * 256 + threadIdx.x) >> 6;   // global wave id
    int lane = threadIdx.x & 63;
    int nwaves = gridDim.x * 4;
    int rgrp = lane >> 3;                 // record-in-group 0..7

    for (int hi = gw; hi < nh; hi += nwaves) {
        int d = heavy[hi];
        unsigned long long P = packed[d];
        int k = (int)(P >> PSHIFT);
        int st = cursor[d] - k;

        float acc[8];
#pragma unroll
        for (int j = 0; j < 8; ++j) acc[j] = 0.f;
        const u32x4* rp = rec + (size_t)st * 8 + lane;
        int nit = (k + 7) >> 3;
        for (int it = 0; it < nit; ++it) {
            int r = it * 8 + rgrp;
            if (r < k) {
                u32x4 v = __builtin_nontemporal_load(rp + (size_t)it * 64);
                acc[0] += bf16_lo(v.x); acc[1] += bf16_hi(v.x);
                acc[2] += bf16_lo(v.y); acc[3] += bf16_hi(v.y);
                acc[4] += bf16_lo(v.z); acc[5] += bf16_hi(v.z);
                acc[6] += bf16_lo(v.w); acc[7] += bf16_hi(v.w);
            }
        }
#pragma unroll
        for (int m = 8; m < 64; m <<= 1) {
#pragma unroll
            for (int j = 0; j < 8; ++j) acc[j] += __shfl_xor(acc[j], m, 64);
        }
        if (lane < 8) {                   // lane writes channels lane*8..+7
            float asum = (float)(P & PMASK) * PINV;
            float rinv = 1.0f / (EPS + asum);
            int b = d >> 18, p = d & (HW - 1);
            float* op = out + (size_t)b * C * HW + (size_t)(lane * 8) * HW + p;
#pragma unroll
            for (int j = 0; j < 8; ++j) op[(size_t)j * HW] = acc[j] * rinv;
        }
    }
}

// ---------------- fallback path (R1, needs only 4 MB ws) ----------------

__global__ __launch_bounds__(256) void init_aa_kernel(float* __restrict__ aa) {
    int i = blockIdx.x * 256 + threadIdx.x;
    aa[i] = EPS;
}

__global__ __launch_bounds__(256) void conv_scatter_kernel(
    const float* __restrict__ x, const float* __restrict__ wmat,
    const float* __restrict__ bias, float* __restrict__ out,
    float* __restrict__ offset, float* __restrict__ dest,
    float* __restrict__ aa)
{
    __shared__ float wsh[3 * C];
    int t = threadIdx.x;
    if (t < 3 * C) wsh[t] = wmat[t];
    __syncthreads();

    int gid = blockIdx.x * 256 + t;
    int b = gid >> 18;
    int p = gid & (HW - 1);
    int hh = p >> 9, ww = p & (W - 1);

    const float* xb = x + (size_t)b * C * HW + p;
    float xv[C];
    float acc0 = 0.f, acc1 = 0.f, acc2 = 0.f;
#pragma unroll
    for (int c = 0; c < C; ++c) {
        float v = xb[(size_t)c * HW];
        xv[c] = v;
        acc0 = fmaf(v, wsh[c], acc0);
        acc1 = fmaf(v, wsh[C + c], acc1);
        acc2 = fmaf(v, wsh[2 * C + c], acc2);
    }
    acc0 += bias[0]; acc1 += bias[1]; acc2 += bias[2];

    float off_y = acc0 * (float)H;
    float off_x = acc1 * (float)W;
    float att = expf(acc2);

    int dy = (int)rintf((float)hh + off_y);
    dy = min(max(dy, 0), H - 1);
    int dx = (int)rintf((float)ww + off_x);
    dx = min(max(dx, 0), W - 1);
    int idx = dy * W + dx;

    size_t ob = (size_t)b * 2 * HW;
    offset[ob + p]      = off_y;
    offset[ob + HW + p] = off_x;
    dest[ob + p]      = (float)dy;
    dest[ob + HW + p] = (float)dx;

    atomicAdd(&aa[b * HW + idx], att);
    float* outp = out + (size_t)b * C * HW + idx;
#pragma unroll
    for (int c = 0; c < C; ++c) {
        atomicAdd(&outp[(size_t)c * HW], xv[c] * att);
    }
}

__global__ __launch_bounds__(256) void normalize_kernel(
    float* __restrict__ out, const float* __restrict__ aa)
{
    int i4 = blockIdx.x * 256 + threadIdx.x;
    size_t e = (size_t)i4 * 4;
    int b = (int)(e / ((size_t)C * HW));
    int p = (int)(e & (size_t)(HW - 1));
    float4 v = *reinterpret_cast<float4*>(out + e);
    const float4 a = *reinterpret_cast<const float4*>(aa + (size_t)b * HW + p);
    v.x /= a.x; v.y /= a.y; v.z /= a.z; v.w /= a.w;
    *reinterpret_cast<float4*>(out + e) = v;
}
} // namespace

extern "C" void kernel_launch(void* const* d_in, const int* in_sizes, int n_in,
                              void* d_out, int out_size, void* d_ws, size_t ws_size,
                              hipStream_t stream) {
    const float* x    = (const float*)d_in[0];
    const float* wmat = (const float*)d_in[1];
    const float* bias = (const float*)d_in[2];

    float* out    = (float*)d_out;                    // [B,C,H,W] (256 MB)
    float* offset = out + (size_t)B * C * HW;         // [B,2,H,W]
    float* dest   = offset + (size_t)B * 2 * HW;      // [B,2,H,W]

    // unsorted records live in the out-region scratch (first 128 MB, dead
    // until gather/heavy overwrite every element of out)
    u32x4* rec_u = (u32x4*)d_out;

    // ws layout (~144.3 MB)
    char* w0 = (char*)d_ws;
    u32x4* rec = (u32x4*)w0;                                        // 128 MB sorted
    int*   idx_a = (int*)(w0 + (size_t)ND * 128);                   // 4 MB
    unsigned long long* packed =
        (unsigned long long*)((char*)idx_a + (size_t)ND * 4);       // 8 MB (zeroed)
    int*   ctrs  = (int*)((char*)packed + (size_t)ND * 8);          // 256 B (zeroed)
    int*   cursor= (int*)((char*)ctrs + 256);                       // 4 MB
    int*   heavy = (int*)((char*)cursor + (size_t)ND * 4);          // 256 KB
    size_t need  = (size_t)(((char*)heavy + HEAVY_CAP * 4) - w0);

    if (ws_size >= need) {
        hipMemsetAsync(packed, 0, (size_t)ND * 8 + 256, stream);    // packed + ctrs
        conv_kernel<<<ND / 256, 256, 0, stream>>>(
            x, wmat, bias, idx_a, packed, rec_u, offset, dest);
        scan_alloc_kernel<<<ND / 256, 256, 0, stream>>>(packed, cursor, &ctrs[0]);
        sortcopy_kernel<<<ND / 256, 256, 0, stream>>>(rec_u, idx_a, cursor, rec);
        gather_kernel<<<2 * ND / 256, 256, 0, stream>>>(
            rec, packed, cursor, out, heavy, &ctrs[1]);
        heavy_kernel<<<4096, 256, 0, stream>>>(
            rec, packed, cursor, out, heavy, &ctrs[1]);
    } else {
        // fallback: R1 path (4 MB ws)
        float* aaf = (float*)d_ws;
        hipMemsetAsync(out, 0, (size_t)B * C * HW * sizeof(float), stream);
        init_aa_kernel<<<B * HW / 256, 256, 0, stream>>>(aaf);
        conv_scatter_kernel<<<B * HW / 256, 256, 0, stream>>>(
            x, wmat, bias, out, offset, dest, aaf);
        normalize_kernel<<<(B * (size_t)C * HW / 4) / 256, 256, 0, stream>>>(out, aaf);
    }
}

// Round 10
// 529.200 us; speedup vs baseline: 1.4557x; 1.0258x over previous
//
#include <hip/hip_runtime.h>

namespace {
constexpr int B = 4, C = 64, H = 512, W = 512;
constexpr int HW = H * W;                 // 2^18
constexpr int ND = B * HW;                // 2^20 sources == destinations
constexpr float EPS = 1e-5f;
constexpr int KT = 16;                    // heavy-destination threshold
constexpr int HEAVY_CAP = 65536;          // >= ND/(KT+1) = 61680, pigeonhole-safe

// packed per-destination accumulator: bits [43..63] = count, [0..42] = Q22.21 sum(att)
constexpr int PSHIFT = 43;
constexpr float PSCALE = 2097152.0f;      // 2^21
constexpr float PINV   = 1.0f / 2097152.0f;
constexpr unsigned long long PMASK = ((1ull << PSHIFT) - 1);

using u32x4 = __attribute__((ext_vector_type(4))) unsigned int;

__device__ __forceinline__ float bf16_lo(unsigned int u) {
    return __uint_as_float(u << 16);
}
__device__ __forceinline__ float bf16_hi(unsigned int u) {
    return __uint_as_float(u & 0xffff0000u);
}
__device__ __forceinline__ unsigned int pack_bf16(float a, float b) {
    unsigned int ua = __float_as_uint(a), ub = __float_as_uint(b);
    ua = (ua + 0x7fffu + ((ua >> 16) & 1u)) >> 16;   // RNE f32->bf16
    ub = (ub + 0x7fffu + ((ub >> 16) & 1u)) >> 16;
    return ua | (ub << 16);
}

// ---------------- fast path ----------------
// conv: 2 threads per pixel (h = channel half). Each keeps xv[32] in regs,
// partial dots combined with one shfl_xor; ONE packed atomic per pixel;
// premultiplied bf16 half-record written by each thread.
__global__ __launch_bounds__(256) void conv_kernel(
    const float* __restrict__ x, const float* __restrict__ wmat,
    const float* __restrict__ bias,
    int* __restrict__ idx_a, unsigned long long* __restrict__ packed,
    u32x4* __restrict__ rec_u,
    float* __restrict__ offset, float* __restrict__ dest)
{
    __shared__ float wsh[3 * C];
    int t = threadIdx.x;
    if (t < 3 * C) wsh[t] = wmat[t];
    __syncthreads();

    int gt = blockIdx.x * 256 + t;
    int s = gt >> 1;                      // pixel id (b<<18 | p)
    int h = gt & 1;                       // channel half
    int b = s >> 18;
    int p = s & (HW - 1);
    int hh = p >> 9, ww = p & (W - 1);

    const float* xb = x + (size_t)b * C * HW + (size_t)(h * 32) * HW + p;
    float xv[32];
    float pa0 = 0.f, pa1 = 0.f, pa2 = 0.f;
#pragma unroll
    for (int c = 0; c < 32; ++c) {
        float v = __builtin_nontemporal_load(xb + (size_t)c * HW);
        xv[c] = v;
        pa0 = fmaf(v, wsh[h * 32 + c], pa0);
        pa1 = fmaf(v, wsh[C + h * 32 + c], pa1);
        pa2 = fmaf(v, wsh[2 * C + h * 32 + c], pa2);
    }
    // pair-combine (lanes differ in bit 0)
    float a0 = pa0 + __shfl_xor(pa0, 1, 64);
    float a1 = pa1 + __shfl_xor(pa1, 1, 64);
    float a2 = pa2 + __shfl_xor(pa2, 1, 64);
    a0 += bias[0]; a1 += bias[1]; a2 += bias[2];

    float oy = a0 * (float)H;             // DOWNSAMPLE = 1.0
    float ox = a1 * (float)W;
    float att = expf(a2);

    int dy = (int)rintf((float)hh + oy);  // RNE == jnp.round
    dy = min(max(dy, 0), H - 1);
    int dx = (int)rintf((float)ww + ox);
    dx = min(max(dx, 0), W - 1);
    int idx = dy * W + dx;

    size_t ob = (size_t)b * 2 * HW;
    if (h == 0) {                         // even lanes: y-planes (coalesced)
        offset[ob + p] = oy;
        dest[ob + p]   = (float)dy;
        idx_a[s] = idx;
        atomicAdd(&packed[(b << 18) | idx],
                  (1ull << PSHIFT) | (unsigned long long)(att * PSCALE));
    } else {                              // odd lanes: x-planes
        offset[ob + HW + p] = ox;
        dest[ob + HW + p]   = (float)dx;
    }

    // premultiplied bf16 half-record: 64B per thread, wave-contiguous 4KB
    u32x4* row = rec_u + (size_t)s * 8 + h * 4;
#pragma unroll
    for (int j = 0; j < 4; ++j) {
        u32x4 u;
        u.x = pack_bf16(xv[j * 8 + 0] * att, xv[j * 8 + 1] * att);
        u.y = pack_bf16(xv[j * 8 + 2] * att, xv[j * 8 + 3] * att);
        u.z = pack_bf16(xv[j * 8 + 4] * att, xv[j * 8 + 5] * att);
        u.w = pack_bf16(xv[j * 8 + 6] * att, xv[j * 8 + 7] * att);
        row[j] = u;
    }
}

__global__ __launch_bounds__(256) void scan_alloc_kernel(
    const unsigned long long* __restrict__ packed,
    int* __restrict__ cursor, int* __restrict__ alloc)
{
    __shared__ int sd[256];
    __shared__ int blockBase;
    int t = threadIdx.x;
    int i = blockIdx.x * 256 + t;
    int c = (int)(packed[i] >> PSHIFT);
    sd[t] = c;
    __syncthreads();
#pragma unroll
    for (int off = 1; off < 256; off <<= 1) {     // Hillis-Steele inclusive
        int v = (t >= off) ? sd[t - off] : 0;
        __syncthreads();
        sd[t] += v;
        __syncthreads();
    }
    if (t == 255) blockBase = atomicAdd(alloc, sd[255]);
    __syncthreads();
    cursor[i] = blockBase + sd[t] - c;            // exclusive start
}

// permutation copy, 2 threads per record (64B halves)
__global__ __launch_bounds__(256) void sortcopy_kernel(
    const u32x4* __restrict__ rec_u, const int* __restrict__ idx_a,
    int* __restrict__ cursor, u32x4* __restrict__ rec)
{
    int gt = blockIdx.x * 256 + threadIdx.x;
    int s = gt >> 1, h = gt & 1;
    int lane = threadIdx.x & 63;
    int d = (s & ~(HW - 1)) | idx_a[s];
    int pos = 0;
    if (h == 0) pos = atomicAdd(&cursor[d], 1);
    pos = __shfl(pos, lane & ~1, 64);             // broadcast from even lane

    const u32x4* src = rec_u + (size_t)s * 8 + h * 4;   // sequential 64B
    u32x4* dst = rec + (size_t)pos * 8 + h * 4;         // scattered, pair=full line
#pragma unroll
    for (int j = 0; j < 4; ++j)
        dst[j] = __builtin_nontemporal_load(src + j);
}

// 2 threads per destination: h = channel half (32 channels each)
__global__ __launch_bounds__(256) void gather_kernel(
    const u32x4* __restrict__ rec, const unsigned long long* __restrict__ packed,
    const int* __restrict__ cursor, float* __restrict__ out,
    int* __restrict__ heavy, int* __restrict__ heavy_n)
{
    int tid = blockIdx.x * 256 + threadIdx.x;
    int d = tid >> 1, h = tid & 1;
    unsigned long long P = packed[d];
    int k = (int)(P >> PSHIFT);
    if (k > KT) {
        if (h == 0) heavy[atomicAdd(heavy_n, 1)] = d;
        return;
    }
    float acc[32];
#pragma unroll
    for (int c = 0; c < 32; ++c) acc[c] = 0.f;
    int st = cursor[d] - k;               // cursor is the CSR end
    const u32x4* rbase = rec + (size_t)st * 8 + h * 4;   // this half's 64B
    for (int i = 0; i < k; ++i) {
#pragma unroll
        for (int j = 0; j < 4; ++j) {
            u32x4 v = __builtin_nontemporal_load(rbase + (size_t)i * 8 + j);
            acc[j * 8 + 0] += bf16_lo(v.x); acc[j * 8 + 1] += bf16_hi(v.x);
            acc[j * 8 + 2] += bf16_lo(v.y); acc[j * 8 + 3] += bf16_hi(v.y);
            acc[j * 8 + 4] += bf16_lo(v.z); acc[j * 8 + 5] += bf16_hi(v.z);
            acc[j * 8 + 6] += bf16_lo(v.w); acc[j * 8 + 7] += bf16_hi(v.w);
        }
    }
    float asum = (float)(P & PMASK) * PINV;
    float rinv = 1.0f / (EPS + asum);
    int b = d >> 18, p = d & (HW - 1);
    float* op = out + (size_t)b * C * HW + (size_t)(h * 32) * HW + p;
#pragma unroll
    for (int c = 0; c < 32; ++c) op[(size_t)c * HW] = acc[c] * rinv;
}

// one WAVE per heavy destination; 8 records (1KB) per wave-iteration
__global__ __launch_bounds__(256) void heavy_kernel(
    const u32x4* __restrict__ rec, const unsigned long long* __restrict__ packed,
    const int* __restrict__ cursor, float* __restrict__ out,
    const int* __restrict__ heavy, const int* __restrict__ heavy_n)
{
    int nh = *heavy_n;
    int gw = (blockIdx.x * 256 + threadIdx.x) >> 6;   // global wave id
    int lane = threadIdx.x & 63;
    int nwaves = gridDim.x * 4;
    int rgrp = lane >> 3;                 // record-in-group 0..7

    for (int hi = gw; hi < nh; hi += nwaves) {
        int d = heavy[hi];
        unsigned long long P = packed[d];
        int k = (int)(P >> PSHIFT);
        int st = cursor[d] - k;

        float acc[8];
#pragma unroll
        for (int j = 0; j < 8; ++j) acc[j] = 0.f;
        const u32x4* rp = rec + (size_t)st * 8 + lane;
        int nit = (k + 7) >> 3;
        for (int it = 0; it < nit; ++it) {
            int r = it * 8 + rgrp;
            if (r < k) {
                u32x4 v = __builtin_nontemporal_load(rp + (size_t)it * 64);
                acc[0] += bf16_lo(v.x); acc[1] += bf16_hi(v.x);
                acc[2] += bf16_lo(v.y); acc[3] += bf16_hi(v.y);
                acc[4] += bf16_lo(v.z); acc[5] += bf16_hi(v.z);
                acc[6] += bf16_lo(v.w); acc[7] += bf16_hi(v.w);
            }
        }
#pragma unroll
        for (int m = 8; m < 64; m <<= 1) {
#pragma unroll
            for (int j = 0; j < 8; ++j) acc[j] += __shfl_xor(acc[j], m, 64);
        }
        if (lane < 8) {                   // lane writes channels lane*8..+7
            float asum = (float)(P & PMASK) * PINV;
            float rinv = 1.0f / (EPS + asum);
            int b = d >> 18, p = d & (HW - 1);
            float* op = out + (size_t)b * C * HW + (size_t)(lane * 8) * HW + p;
#pragma unroll
            for (int j = 0; j < 8; ++j) op[(size_t)j * HW] = acc[j] * rinv;
        }
    }
}

// ---------------- fallback path (R1, needs only 4 MB ws) ----------------

__global__ __launch_bounds__(256) void init_aa_kernel(float* __restrict__ aa) {
    int i = blockIdx.x * 256 + threadIdx.x;
    aa[i] = EPS;
}

__global__ __launch_bounds__(256) void conv_scatter_kernel(
    const float* __restrict__ x, const float* __restrict__ wmat,
    const float* __restrict__ bias, float* __restrict__ out,
    float* __restrict__ offset, float* __restrict__ dest,
    float* __restrict__ aa)
{
    __shared__ float wsh[3 * C];
    int t = threadIdx.x;
    if (t < 3 * C) wsh[t] = wmat[t];
    __syncthreads();

    int gid = blockIdx.x * 256 + t;
    int b = gid >> 18;
    int p = gid & (HW - 1);
    int hh = p >> 9, ww = p & (W - 1);

    const float* xb = x + (size_t)b * C * HW + p;
    float xv[C];
    float acc0 = 0.f, acc1 = 0.f, acc2 = 0.f;
#pragma unroll
    for (int c = 0; c < C; ++c) {
        float v = xb[(size_t)c * HW];
        xv[c] = v;
        acc0 = fmaf(v, wsh[c], acc0);
        acc1 = fmaf(v, wsh[C + c], acc1);
        acc2 = fmaf(v, wsh[2 * C + c], acc2);
    }
    acc0 += bias[0]; acc1 += bias[1]; acc2 += bias[2];

    float off_y = acc0 * (float)H;
    float off_x = acc1 * (float)W;
    float att = expf(acc2);

    int dy = (int)rintf((float)hh + off_y);
    dy = min(max(dy, 0), H - 1);
    int dx = (int)rintf((float)ww + off_x);
    dx = min(max(dx, 0), W - 1);
    int idx = dy * W + dx;

    size_t ob = (size_t)b * 2 * HW;
    offset[ob + p]      = off_y;
    offset[ob + HW + p] = off_x;
    dest[ob + p]      = (float)dy;
    dest[ob + HW + p] = (float)dx;

    atomicAdd(&aa[b * HW + idx], att);
    float* outp = out + (size_t)b * C * HW + idx;
#pragma unroll
    for (int c = 0; c < C; ++c) {
        atomicAdd(&outp[(size_t)c * HW], xv[c] * att);
    }
}

__global__ __launch_bounds__(256) void normalize_kernel(
    float* __restrict__ out, const float* __restrict__ aa)
{
    int i4 = blockIdx.x * 256 + threadIdx.x;
    size_t e = (size_t)i4 * 4;
    int b = (int)(e / ((size_t)C * HW));
    int p = (int)(e & (size_t)(HW - 1));
    float4 v = *reinterpret_cast<float4*>(out + e);
    const float4 a = *reinterpret_cast<const float4*>(aa + (size_t)b * HW + p);
    v.x /= a.x; v.y /= a.y; v.z /= a.z; v.w /= a.w;
    *reinterpret_cast<float4*>(out + e) = v;
}
} // namespace

extern "C" void kernel_launch(void* const* d_in, const int* in_sizes, int n_in,
                              void* d_out, int out_size, void* d_ws, size_t ws_size,
                              hipStream_t stream) {
    const float* x    = (const float*)d_in[0];
    const float* wmat = (const float*)d_in[1];
    const float* bias = (const float*)d_in[2];

    float* out    = (float*)d_out;                    // [B,C,H,W] (256 MB)
    float* offset = out + (size_t)B * C * HW;         // [B,2,H,W]
    float* dest   = offset + (size_t)B * 2 * HW;      // [B,2,H,W]

    // unsorted records live in the out-region scratch (first 128 MB, dead
    // until gather/heavy overwrite every element of out)
    u32x4* rec_u = (u32x4*)d_out;

    // ws layout (~144.3 MB)
    char* w0 = (char*)d_ws;
    u32x4* rec = (u32x4*)w0;                                        // 128 MB sorted
    int*   idx_a = (int*)(w0 + (size_t)ND * 128);                   // 4 MB
    unsigned long long* packed =
        (unsigned long long*)((char*)idx_a + (size_t)ND * 4);       // 8 MB (zeroed)
    int*   ctrs  = (int*)((char*)packed + (size_t)ND * 8);          // 256 B (zeroed)
    int*   cursor= (int*)((char*)ctrs + 256);                       // 4 MB
    int*   heavy = (int*)((char*)cursor + (size_t)ND * 4);          // 256 KB
    size_t need  = (size_t)(((char*)heavy + HEAVY_CAP * 4) - w0);

    if (ws_size >= need) {
        hipMemsetAsync(packed, 0, (size_t)ND * 8 + 256, stream);    // packed + ctrs
        conv_kernel<<<2 * ND / 256, 256, 0, stream>>>(
            x, wmat, bias, idx_a, packed, rec_u, offset, dest);
        scan_alloc_kernel<<<ND / 256, 256, 0, stream>>>(packed, cursor, &ctrs[0]);
        sortcopy_kernel<<<2 * ND / 256, 256, 0, stream>>>(rec_u, idx_a, cursor, rec);
        gather_kernel<<<2 * ND / 256, 256, 0, stream>>>(
            rec, packed, cursor, out, heavy, &ctrs[1]);
        heavy_kernel<<<4096, 256, 0, stream>>>(
            rec, packed, cursor, out, heavy, &ctrs[1]);
    } else {
        // fallback: R1 path (4 MB ws)
        float* aaf = (float*)d_ws;
        hipMemsetAsync(out, 0, (size_t)B * C * HW * sizeof(float), stream);
        init_aa_kernel<<<B * HW / 256, 256, 0, stream>>>(aaf);
        conv_scatter_kernel<<<B * HW / 256, 256, 0, stream>>>(
            x, wmat, bias, out, offset, dest, aaf);
        normalize_kernel<<<(B * (size_t)C * HW / 4) / 256, 256, 0, stream>>>(out, aaf);
    }
}

// Round 15
// 443.268 us; speedup vs baseline: 1.7379x; 1.1939x over previous
//
#include <hip/hip_runtime.h>

namespace {
constexpr int B = 4, C = 64, H = 512, W = 512;
constexpr int HW = H * W;                 // 2^18
constexpr int ND = B * HW;                // 2^20 sources == destinations
constexpr float EPS = 1e-5f;
constexpr int KT = 16;                    // heavy-destination threshold
constexpr int HEAVY_CAP = 65536;          // >= ND/(KT+1) = 61680, pigeonhole-safe

// packed per-destination accumulator: bits [43..63] = count, [0..42] = Q22.21 sum(att)
constexpr int PSHIFT = 43;
constexpr float PSCALE = 2097152.0f;      // 2^21
constexpr float PINV   = 1.0f / 2097152.0f;
constexpr unsigned long long PMASK = ((1ull << PSHIFT) - 1);

using u32x4 = __attribute__((ext_vector_type(4))) unsigned int;
using f32x2 = __attribute__((ext_vector_type(2))) float;

// fp8 e4m3 (OCP) HW convert helpers — record payload only (out is the only
// output touched by this rounding; offset/dest/denominator stay exact f32)
__device__ __forceinline__ unsigned int pack4_fp8(float a, float b, float c, float d) {
    int w = 0;
    w = __builtin_amdgcn_cvt_pk_fp8_f32(a, b, w, false);  // bytes 0,1
    w = __builtin_amdgcn_cvt_pk_fp8_f32(c, d, w, true);   // bytes 2,3
    return (unsigned int)w;
}

// ---------------- fast path ----------------
// conv: 2 threads per pixel (h = channel half). Each keeps xv[32] in regs,
// partial dots combined with one shfl_xor; ONE packed atomic per pixel;
// premultiplied fp8 half-record (32B) written by each thread.
__global__ __launch_bounds__(256) void conv_kernel(
    const float* __restrict__ x, const float* __restrict__ wmat,
    const float* __restrict__ bias,
    int* __restrict__ idx_a, unsigned long long* __restrict__ packed,
    u32x4* __restrict__ rec_u,
    float* __restrict__ offset, float* __restrict__ dest)
{
    __shared__ float wsh[3 * C];
    int t = threadIdx.x;
    if (t < 3 * C) wsh[t] = wmat[t];
    __syncthreads();

    int gt = blockIdx.x * 256 + t;
    int s = gt >> 1;                      // pixel id (b<<18 | p)
    int h = gt & 1;                       // channel half
    int b = s >> 18;
    int p = s & (HW - 1);
    int hh = p >> 9, ww = p & (W - 1);

    const float* xb = x + (size_t)b * C * HW + (size_t)(h * 32) * HW + p;
    float xv[32];
    float pa0 = 0.f, pa1 = 0.f, pa2 = 0.f;
#pragma unroll
    for (int c = 0; c < 32; ++c) {
        float v = __builtin_nontemporal_load(xb + (size_t)c * HW);
        xv[c] = v;
        pa0 = fmaf(v, wsh[h * 32 + c], pa0);
        pa1 = fmaf(v, wsh[C + h * 32 + c], pa1);
        pa2 = fmaf(v, wsh[2 * C + h * 32 + c], pa2);
    }
    // pair-combine (lanes differ in bit 0)
    float a0 = pa0 + __shfl_xor(pa0, 1, 64);
    float a1 = pa1 + __shfl_xor(pa1, 1, 64);
    float a2 = pa2 + __shfl_xor(pa2, 1, 64);
    a0 += bias[0]; a1 += bias[1]; a2 += bias[2];

    float oy = a0 * (float)H;             // DOWNSAMPLE = 1.0
    float ox = a1 * (float)W;
    float att = expf(a2);

    int dy = (int)rintf((float)hh + oy);  // RNE == jnp.round
    dy = min(max(dy, 0), H - 1);
    int dx = (int)rintf((float)ww + ox);
    dx = min(max(dx, 0), W - 1);
    int idx = dy * W + dx;

    size_t ob = (size_t)b * 2 * HW;
    if (h == 0) {                         // even lanes: y-planes (coalesced)
        offset[ob + p] = oy;
        dest[ob + p]   = (float)dy;
        idx_a[s] = idx;
        atomicAdd(&packed[(b << 18) | idx],
                  (1ull << PSHIFT) | (unsigned long long)(att * PSCALE));
    } else {                              // odd lanes: x-planes
        offset[ob + HW + p] = ox;
        dest[ob + HW + p]   = (float)dx;
    }

    // premultiplied fp8 half-record: 32B per thread (record = 64B = 4 u32x4 / 2)
    u32x4* row = rec_u + (size_t)s * 4 + h * 2;
#pragma unroll
    for (int j = 0; j < 2; ++j) {         // j-th 16-channel chunk
        u32x4 u;
#pragma unroll
        for (int q = 0; q < 4; ++q)
            u[q] = pack4_fp8(xv[j * 16 + q * 4 + 0] * att,
                             xv[j * 16 + q * 4 + 1] * att,
                             xv[j * 16 + q * 4 + 2] * att,
                             xv[j * 16 + q * 4 + 3] * att);
        row[j] = u;
    }
}

__global__ __launch_bounds__(256) void scan_alloc_kernel(
    const unsigned long long* __restrict__ packed,
    int* __restrict__ cursor, int* __restrict__ alloc)
{
    __shared__ int sd[256];
    __shared__ int blockBase;
    int t = threadIdx.x;
    int i = blockIdx.x * 256 + t;
    int c = (int)(packed[i] >> PSHIFT);
    sd[t] = c;
    __syncthreads();
#pragma unroll
    for (int off = 1; off < 256; off <<= 1) {     // Hillis-Steele inclusive
        int v = (t >= off) ? sd[t - off] : 0;
        __syncthreads();
        sd[t] += v;
        __syncthreads();
    }
    if (t == 255) blockBase = atomicAdd(alloc, sd[255]);
    __syncthreads();
    cursor[i] = blockBase + sd[t] - c;            // exclusive start
}

// permutation copy, 2 threads per record (32B halves)
__global__ __launch_bounds__(256) void sortcopy_kernel(
    const u32x4* __restrict__ rec_u, const int* __restrict__ idx_a,
    int* __restrict__ cursor, u32x4* __restrict__ rec)
{
    int gt = blockIdx.x * 256 + threadIdx.x;
    int s = gt >> 1, h = gt & 1;
    int lane = threadIdx.x & 63;
    int d = (s & ~(HW - 1)) | idx_a[s];
    int pos = 0;
    if (h == 0) pos = atomicAdd(&cursor[d], 1);
    pos = __shfl(pos, lane & ~1, 64);             // broadcast from even lane

    const u32x4* src = rec_u + (size_t)s * 4 + h * 2;   // sequential 32B
    u32x4* dst = rec + (size_t)pos * 4 + h * 2;         // scattered, pair=64B
#pragma unroll
    for (int j = 0; j < 2; ++j)
        dst[j] = __builtin_nontemporal_load(src + j);
}

// 2 threads per destination: h = channel half (32 channels each)
__global__ __launch_bounds__(256) void gather_kernel(
    const u32x4* __restrict__ rec, const unsigned long long* __restrict__ packed,
    const int* __restrict__ cursor, float* __restrict__ out,
    int* __restrict__ heavy, int* __restrict__ heavy_n)
{
    int tid = blockIdx.x * 256 + threadIdx.x;
    int d = tid >> 1, h = tid & 1;
    unsigned long long P = packed[d];
    int k = (int)(P >> PSHIFT);
    if (k > KT) {
        if (h == 0) heavy[atomicAdd(heavy_n, 1)] = d;
        return;
    }
    float acc[32];
#pragma unroll
    for (int c = 0; c < 32; ++c) acc[c] = 0.f;
    int st = cursor[d] - k;               // cursor is the CSR end
    const u32x4* rbase = rec + (size_t)st * 4 + h * 2;   // this half's 32B
    for (int i = 0; i < k; ++i) {
#pragma unroll
        for (int j = 0; j < 2; ++j) {
            u32x4 v = __builtin_nontemporal_load(rbase + (size_t)i * 4 + j);
#pragma unroll
            for (int q = 0; q < 4; ++q) {
                f32x2 lo = __builtin_amdgcn_cvt_pk_f32_fp8((int)v[q], false);
                f32x2 hi = __builtin_amdgcn_cvt_pk_f32_fp8((int)v[q], true);
                acc[j * 16 + q * 4 + 0] += lo[0];
                acc[j * 16 + q * 4 + 1] += lo[1];
                acc[j * 16 + q * 4 + 2] += hi[0];
                acc[j * 16 + q * 4 + 3] += hi[1];
            }
        }
    }
    float asum = (float)(P & PMASK) * PINV;
    float rinv = 1.0f / (EPS + asum);
    int b = d >> 18, p = d & (HW - 1);
    float* op = out + (size_t)b * C * HW + (size_t)(h * 32) * HW + p;
#pragma unroll
    for (int c = 0; c < 32; ++c) op[(size_t)c * HW] = acc[c] * rinv;
}

// one WAVE per heavy destination; 16 records (1KB) per wave-iteration
__global__ __launch_bounds__(256) void heavy_kernel(
    const u32x4* __restrict__ rec, const unsigned long long* __restrict__ packed,
    const int* __restrict__ cursor, float* __restrict__ out,
    const int* __restrict__ heavy, const int* __restrict__ heavy_n)
{
    int nh = *heavy_n;
    int gw = (blockIdx.x * 256 + threadIdx.x) >> 6;   // global wave id
    int lane = threadIdx.x & 63;
    int nwaves = gridDim.x * 4;
    int rgrp = lane >> 2;                 // record-in-group 0..15
    // chunk (lane & 3) = 16 channels of the record

    for (int hi = gw; hi < nh; hi += nwaves) {
        int d = heavy[hi];
        unsigned long long P = packed[d];
        int k = (int)(P >> PSHIFT);
        int st = cursor[d] - k;

        float acc[16];
#pragma unroll
        for (int j = 0; j < 16; ++j) acc[j] = 0.f;
        const u32x4* rp = rec + (size_t)st * 4 + lane;
        int nit = (k + 15) >> 4;
        for (int it = 0; it < nit; ++it) {
            int r = it * 16 + rgrp;
            if (r < k) {
                u32x4 v = __builtin_nontemporal_load(rp + (size_t)it * 64);
#pragma unroll
                for (int q = 0; q < 4; ++q) {
                    f32x2 lo = __builtin_amdgcn_cvt_pk_f32_fp8((int)v[q], false);
                    f32x2 hi = __builtin_amdgcn_cvt_pk_f32_fp8((int)v[q], true);
                    acc[q * 4 + 0] += lo[0];
                    acc[q * 4 + 1] += lo[1];
                    acc[q * 4 + 2] += hi[0];
                    acc[q * 4 + 3] += hi[1];
                }
            }
        }
        // reduce across the 16 record-groups (lane bits 2..5); chunk preserved
#pragma unroll
        for (int m = 4; m < 64; m <<= 1) {
#pragma unroll
            for (int j = 0; j < 16; ++j) acc[j] += __shfl_xor(acc[j], m, 64);
        }
        if (lane < 4) {                   // lane writes channels lane*16..+15
            float asum = (float)(P & PMASK) * PINV;
            float rinv = 1.0f / (EPS + asum);
            int b = d >> 18, p = d & (HW - 1);
            float* op = out + (size_t)b * C * HW + (size_t)(lane * 16) * HW + p;
#pragma unroll
            for (int j = 0; j < 16; ++j) op[(size_t)j * HW] = acc[j] * rinv;
        }
    }
}

// ---------------- fallback path (R1, needs only 4 MB ws) ----------------

__global__ __launch_bounds__(256) void init_aa_kernel(float* __restrict__ aa) {
    int i = blockIdx.x * 256 + threadIdx.x;
    aa[i] = EPS;
}

__global__ __launch_bounds__(256) void conv_scatter_kernel(
    const float* __restrict__ x, const float* __restrict__ wmat,
    const float* __restrict__ bias, float* __restrict__ out,
    float* __restrict__ offset, float* __restrict__ dest,
    float* __restrict__ aa)
{
    __shared__ float wsh[3 * C];
    int t = threadIdx.x;
    if (t < 3 * C) wsh[t] = wmat[t];
    __syncthreads();

    int gid = blockIdx.x * 256 + t;
    int b = gid >> 18;
    int p = gid & (HW - 1);
    int hh = p >> 9, ww = p & (W - 1);

    const float* xb = x + (size_t)b * C * HW + p;
    float xv[C];
    float acc0 = 0.f, acc1 = 0.f, acc2 = 0.f;
#pragma unroll
    for (int c = 0; c < C; ++c) {
        float v = xb[(size_t)c * HW];
        xv[c] = v;
        acc0 = fmaf(v, wsh[c], acc0);
        acc1 = fmaf(v, wsh[C + c], acc1);
        acc2 = fmaf(v, wsh[2 * C + c], acc2);
    }
    acc0 += bias[0]; acc1 += bias[1]; acc2 += bias[2];

    float off_y = acc0 * (float)H;
    float off_x = acc1 * (float)W;
    float att = expf(acc2);

    int dy = (int)rintf((float)hh + off_y);
    dy = min(max(dy, 0), H - 1);
    int dx = (int)rintf((float)ww + off_x);
    dx = min(max(dx, 0), W - 1);
    int idx = dy * W + dx;

    size_t ob = (size_t)b * 2 * HW;
    offset[ob + p]      = off_y;
    offset[ob + HW + p] = off_x;
    dest[ob + p]      = (float)dy;
    dest[ob + HW + p] = (float)dx;

    atomicAdd(&aa[b * HW + idx], att);
    float* outp = out + (size_t)b * C * HW + idx;
#pragma unroll
    for (int c = 0; c < C; ++c) {
        atomicAdd(&outp[(size_t)c * HW], xv[c] * att);
    }
}

__global__ __launch_bounds__(256) void normalize_kernel(
    float* __restrict__ out, const float* __restrict__ aa)
{
    int i4 = blockIdx.x * 256 + threadIdx.x;
    size_t e = (size_t)i4 * 4;
    int b = (int)(e / ((size_t)C * HW));
    int p = (int)(e & (size_t)(HW - 1));
    float4 v = *reinterpret_cast<float4*>(out + e);
    const float4 a = *reinterpret_cast<const float4*>(aa + (size_t)b * HW + p);
    v.x /= a.x; v.y /= a.y; v.z /= a.z; v.w /= a.w;
    *reinterpret_cast<float4*>(out + e) = v;
}
} // namespace

extern "C" void kernel_launch(void* const* d_in, const int* in_sizes, int n_in,
                              void* d_out, int out_size, void* d_ws, size_t ws_size,
                              hipStream_t stream) {
    const float* x    = (const float*)d_in[0];
    const float* wmat = (const float*)d_in[1];
    const float* bias = (const float*)d_in[2];

    float* out    = (float*)d_out;                    // [B,C,H,W] (256 MB)
    float* offset = out + (size_t)B * C * HW;         // [B,2,H,W]
    float* dest   = offset + (size_t)B * 2 * HW;      // [B,2,H,W]

    // unsorted fp8 records live in the out-region scratch (first 64 MB, dead
    // until gather/heavy overwrite every element of out)
    u32x4* rec_u = (u32x4*)d_out;

    // ws layout (~80.5 MB)
    char* w0 = (char*)d_ws;
    u32x4* rec = (u32x4*)w0;                                        // 64 MB sorted fp8
    int*   idx_a = (int*)(w0 + (size_t)ND * 64);                    // 4 MB
    unsigned long long* packed =
        (unsigned long long*)((char*)idx_a + (size_t)ND * 4);       // 8 MB (zeroed)
    int*   ctrs  = (int*)((char*)packed + (size_t)ND * 8);          // 256 B (zeroed)
    int*   cursor= (int*)((char*)ctrs + 256);                       // 4 MB
    int*   heavy = (int*)((char*)cursor + (size_t)ND * 4);          // 256 KB
    size_t need  = (size_t)(((char*)heavy + HEAVY_CAP * 4) - w0);

    if (ws_size >= need) {
        hipMemsetAsync(packed, 0, (size_t)ND * 8 + 256, stream);    // packed + ctrs
        conv_kernel<<<2 * ND / 256, 256, 0, stream>>>(
            x, wmat, bias, idx_a, packed, rec_u, offset, dest);
        scan_alloc_kernel<<<ND / 256, 256, 0, stream>>>(packed, cursor, &ctrs[0]);
        sortcopy_kernel<<<2 * ND / 256, 256, 0, stream>>>(rec_u, idx_a, cursor, rec);
        gather_kernel<<<2 * ND / 256, 256, 0, stream>>>(
            rec, packed, cursor, out, heavy, &ctrs[1]);
        heavy_kernel<<<4096, 256, 0, stream>>>(
            rec, packed, cursor, out, heavy, &ctrs[1]);
    } else {
        // fallback: R1 path (4 MB ws)
        float* aaf = (float*)d_ws;
        hipMemsetAsync(out, 0, (size_t)B * C * HW * sizeof(float), stream);
        init_aa_kernel<<<B * HW / 256, 256, 0, stream>>>(aaf);
        conv_scatter_kernel<<<B * HW / 256, 256, 0, stream>>>(
            x, wmat, bias, out, offset, dest, aaf);
        normalize_kernel<<<(B * (size_t)C * HW / 4) / 256, 256, 0, stream>>>(out, aaf);
    }
}